// Round 2
// baseline (331.460 us; speedup 1.0000x reference)
//
#include <hip/hip_runtime.h>

// upfirdn2d: up=(2,2), down=(1,1), pad=((2,1),(2,1)), 4x4 kernel, gain=4
// x: (16,64,128,128) f32 -> out: (16,64,255,255) f32
//
// v3: SEPARABLE + 32-row tiles.
// k = outer(k1d,k1d)/64 is rank-1, so w[py][px][a][b] = kv[py][a]*kh[px][b]
// with kv[py][a] = 4*k[ry][0]/k[0][0], kh[px][b] = k[0][rx] (exact in fp32:
// every factor is n/2^m). Horizontal 2-tap first -> H(r,ox); each H is reused
// by two output rows (vertical 2-tap), cutting FMAs 4->3 per output.
//
// Block = 32 output rows x 255 cols of one plane (8192 blocks total).
//   c    = tid & 127 : output column pair (ox = 2c, 2c+1)
//   half = tid >> 7  : row half (rows oy0+16*half .. +16) — wave-uniform
// Stage 18 input rows in LDS (stride 132, aligned float4 writes, zero pad at
// col 3 for ix=-1). Per j (2 output rows x 2 cols): 3 ds_read_b32 (consecutive
// per lane = conflict-free, immediate offsets), 12 VALU, 4 coalesced dword
// stores. Rolling H registers down the column.

#define IN_H 128
#define IN_W 128
#define OUT_H 255
#define OUT_W 255
#define LDS_STRIDE 132         // data at cols [4..131] = ix 0..127; col 3 = zero pad
#define MAX_IN_ROWS 18

__global__ __launch_bounds__(256) void upfirdn2d_kernel(
    const float* __restrict__ x,
    const float* __restrict__ k,
    float* __restrict__ out)
{
    __shared__ float li[MAX_IN_ROWS * LDS_STRIDE + 8];

    const int tid   = threadIdx.x;
    const int tile  = blockIdx.x;
    const int plane = blockIdx.y;

    // --- separable weights (issue these tiny loads early; L2-resident) ---
    const float k00 = k[0];
    const float inv = 4.0f / k00;                 // 256, exact
    const float kv00 = k[12] * inv;               // py=0,a=0 -> ry=3
    const float kv01 = k[4]  * inv;               // py=0,a=1 -> ry=1
    const float kv10 = k[8]  * inv;               // py=1,a=0 -> ry=2
    const float kv11 = 4.0f;                      // py=1,a=1 -> ry=0 (k[0]*inv)
    const float kh00 = k[3], kh01 = k[1];         // px=0: b=0->rx3, b=1->rx1
    const float kh10 = k[2], kh11 = k00;          // px=1: b=0->rx2, b=1->rx0

    const int iy_lo = 16 * tile - 1;
    const int iy_hi = min(IN_H - 1, 16 * tile + 16);
    const int n_in  = iy_hi - iy_lo + 1;          // 18 (17 on last tile)

    // --- stage input rows into LDS (aligned float4 writes) ---
    {
        const float4* xp4 = (const float4*)(x + (size_t)plane * (IN_H * IN_W));
        const int nslots = n_in * (IN_W / 4);     // <= 576
        for (int s = tid; s < nslots; s += 256) {
            const int row = s >> 5;
            const int c4  = s & 31;
            const int iy  = iy_lo + row;
            float4 v = make_float4(0.f, 0.f, 0.f, 0.f);
            if (iy >= 0) v = xp4[iy * (IN_W / 4) + c4];
            *(float4*)&li[row * LDS_STRIDE + 4 + (c4 << 2)] = v;
        }
        if (tid < MAX_IN_ROWS) li[tid * LDS_STRIDE + 3] = 0.0f;   // ix=-1 pad
    }
    __syncthreads();

    const int c    = tid & 127;                   // column pair: ox = 2c, 2c+1
    const int half = tid >> 7;                    // wave-uniform row half
    const bool last_c = (c == 127);               // ox=255 doesn't exist

    // taps for this thread: LDS cols (3+c)+{0,1,2} = input ix {c-1, c, c+1}
    const float* lb = &li[(half << 3) * LDS_STRIDE + 3 + c];

    // prologue: H for rows A (input r_start-1) and B (r_start)
    float t0 = lb[0], t1 = lb[1], t2 = lb[2];
    float hAe = kh00 * t0 + kh01 * t1;
    float hAo = kh10 * t1 + kh11 * t2;
    t0 = lb[LDS_STRIDE]; t1 = lb[LDS_STRIDE + 1]; t2 = lb[LDS_STRIDE + 2];
    float hBe = kh00 * t0 + kh01 * t1;
    float hBo = kh10 * t1 + kh11 * t2;

    const int oy_start = (tile << 5) + (half << 4);
    float* op = out + (size_t)plane * (OUT_H * OUT_W)
                    + (size_t)oy_start * OUT_W + (c << 1);

#pragma unroll
    for (int j = 0; j < 8; ++j) {
        // even output row oy_start+2j: vertical taps A (r-1), B (r)
        op[0] = kv00 * hAe + kv01 * hBe;
        if (!last_c) op[1] = kv00 * hAo + kv01 * hBo;

        // fetch row C (input r+1), compute its H
        float hCe = 0.f, hCo = 0.f;
        if ((half << 3) + j + 2 < n_in) {         // wave-uniform
            const float* lc = lb + (j + 2) * LDS_STRIDE;
            t0 = lc[0]; t1 = lc[1]; t2 = lc[2];
            hCe = kh00 * t0 + kh01 * t1;
            hCo = kh10 * t1 + kh11 * t2;
        }

        // odd output row oy_start+2j+1: vertical taps B (r), C (r+1)
        if (oy_start + 2 * j + 1 < OUT_H) {       // wave-uniform (last tile only)
            op[OUT_W]     = kv10 * hBe + kv11 * hCe;
            if (!last_c) op[OUT_W + 1] = kv10 * hBo + kv11 * hCo;
        }

        hAe = hBe; hAo = hBo; hBe = hCe; hBo = hCo;
        op += 2 * OUT_W;
    }
}

extern "C" void kernel_launch(void* const* d_in, const int* in_sizes, int n_in,
                              void* d_out, int out_size, void* d_ws, size_t ws_size,
                              hipStream_t stream) {
    const float* x = (const float*)d_in[0];
    const float* k = (const float*)d_in[1];
    float* out = (float*)d_out;

    dim3 block(256, 1, 1);
    dim3 grid(8, 1024, 1);     // 32-row tiles per plane x planes (16*64)
    upfirdn2d_kernel<<<grid, block, 0, stream>>>(x, k, out);
}

// Round 3
// 311.908 us; speedup vs baseline: 1.0627x; 1.0627x over previous
//
#include <hip/hip_runtime.h>

// upfirdn2d: up=(2,2), down=(1,1), pad=((2,1),(2,1)), 4x4 kernel, gain=4
// x: (16,64,128,128) f32 -> out: (16,64,255,255) f32
//
// v4 = v2 structure (thread = output column, stride-1 lane stores) + separable
// weights + compile-time tile specialization.
//
// k = outer(k1d,k1d)/64 is rank-1: w[py][px][a][b] = kv[py][a]*kh[px][b] with
// kv[py][a] = 4*k[ry*4]/k[0], kh[px][b] = k[rx]  (verified by v3 refcheck).
// Per thread (fixed column parity px): one H = kh0*t0+kh1*t1 per input row,
// reused by the two adjacent output rows -> per 2 output rows: 2 LDS dwords
// (2-lane-shared consecutive cols = conflict-free) + 6 VALU + 2 coalesced
// dword stores.
//
// Block = 16 output rows x 255 cols of one plane (grid 16x1024). Stage the 10
// needed input rows in LDS (aligned float4 writes, stride 132, zero pad at
// col 3 for the ix=-1 tap). Tiles 0..14 run a fully-unguarded unrolled loop
// (n_in=10, nrows=16 as template constants -> all immediate offsets).

#define IN_H 128
#define IN_W 128
#define OUT_H 255
#define OUT_W 255
#define NTILES 16
#define LDS_STRIDE 132         // data at cols [4..131] = ix 0..127; col 3 = zero pad
#define MAX_IN_ROWS 10

template<int N_IN, int NROWS>
__device__ __forceinline__ void compute_cols(
    const float* __restrict__ lb, float* __restrict__ op,
    float kh0, float kh1, float kv00, float kv01, float kv10, float kv11)
{
    // rolling horizontal-filter values: A = input row j, B = j+1, C = j+2
    float t0 = lb[0], t1 = lb[1];
    float hA = kh0 * t0 + kh1 * t1;
    t0 = lb[LDS_STRIDE]; t1 = lb[LDS_STRIDE + 1];
    float hB = kh0 * t0 + kh1 * t1;

#pragma unroll
    for (int j = 0; j < 8; ++j) {
        // even output row (2j): vertical taps A, B
        op[0] = kv00 * hA + kv01 * hB;

        float hC = 0.f;
        if (j + 2 < N_IN) {                       // compile-time
            t0 = lb[(j + 2) * LDS_STRIDE];
            t1 = lb[(j + 2) * LDS_STRIDE + 1];
            hC = kh0 * t0 + kh1 * t1;
        }

        // odd output row (2j+1): vertical taps B, C
        if (2 * j + 1 < NROWS) {                  // compile-time
            op[OUT_W] = kv10 * hB + kv11 * hC;
        }

        hA = hB; hB = hC;
        op += 2 * OUT_W;
    }
}

__global__ __launch_bounds__(256) void upfirdn2d_kernel(
    const float* __restrict__ x,
    const float* __restrict__ k,
    float* __restrict__ out)
{
    __shared__ float li[MAX_IN_ROWS * LDS_STRIDE];

    const int tid   = threadIdx.x;
    const int tile  = blockIdx.x;
    const int plane = blockIdx.y;

    // separable weights (tiny L2-resident loads; done during staging latency)
    const float k00 = k[0], k01 = k[1], k02 = k[2], k03 = k[3];
    const float inv  = 4.0f / k00;                // 256, exact
    const float kv00 = k[12] * inv;               // ry=3
    const float kv01 = k[4]  * inv;               // ry=1
    const float kv10 = k[8]  * inv;               // ry=2
    const float kv11 = 4.0f;                      // ry=0
    const int iy_lo  = (tile << 3) - 1;
    const int iy_hi  = min(IN_H - 1, (tile << 3) + 8);
    const int n_in   = iy_hi - iy_lo + 1;         // 10 (9 on tile 15)

    // --- stage input rows iy_lo..iy_hi into LDS (aligned float4 writes) ---
    {
        const float4* xp4 = (const float4*)(x + (size_t)plane * (IN_H * IN_W));
        const int nslots = n_in * (IN_W / 4);     // <= 320
        for (int s = tid; s < nslots; s += 256) {
            const int row = s >> 5;
            const int c4  = s & 31;
            const int iy  = iy_lo + row;
            float4 v = make_float4(0.f, 0.f, 0.f, 0.f);
            if (iy >= 0) v = xp4[iy * (IN_W / 4) + c4];
            *(float4*)&li[row * LDS_STRIDE + 4 + (c4 << 2)] = v;
        }
        if (tid < MAX_IN_ROWS) li[tid * LDS_STRIDE + 3] = 0.0f;   // ix=-1 pad
    }
    __syncthreads();

    if (tid >= OUT_W) return;                     // 255 compute lanes

    // thread = output column; px fixed -> horizontal weights in registers
    const int px = tid & 1;
    const float kh0 = px ? k02 : k03;
    const float kh1 = px ? k00 : k01;

    // LDS cols (3 + (tid>>1) + px) + {0,1} = input ix {ix0, ix0+1}
    const float* lb = &li[3 + (tid >> 1) + px];
    float* op = out + (size_t)plane * (OUT_H * OUT_W)
                    + (size_t)(tile << 4) * OUT_W + tid;

    if (tile < NTILES - 1) {
        compute_cols<10, 16>(lb, op, kh0, kh1, kv00, kv01, kv10, kv11);
    } else {
        compute_cols<9, 15>(lb, op, kh0, kh1, kv00, kv01, kv10, kv11);
    }
}

extern "C" void kernel_launch(void* const* d_in, const int* in_sizes, int n_in,
                              void* d_out, int out_size, void* d_ws, size_t ws_size,
                              hipStream_t stream) {
    const float* x = (const float*)d_in[0];
    const float* k = (const float*)d_in[1];
    float* out = (float*)d_out;

    dim3 block(256, 1, 1);
    dim3 grid(NTILES, 1024, 1);    // 16-row tiles per plane x planes (16*64)
    upfirdn2d_kernel<<<grid, block, 0, stream>>>(x, k, out);
}